// Round 1
// baseline (11906.103 us; speedup 1.0000x reference)
//
#include <hip/hip_runtime.h>
#include <hip/hip_bf16.h>
#include <math.h>

// Problem constants (from reference)
#define LAYERS 4
#define IDIM 256
#define HDIM 512
#define NH 8
#define HD 64
#define FF 1024
#define SEQ 1024
#define BATCH 8
#define EPS 1e-5f
#define NEG -1e9f

// ---------------------------------------------------------------------------
// nodes (S,B,I) -> xt (B*S, I) row-major
__global__ __launch_bounds__(256) void transpose_nodes(const float* __restrict__ nodes,
                                                       float* __restrict__ xt) {
    size_t idx = (size_t)blockIdx.x * 256 + threadIdx.x;   // total S*B*I
    int i  = idx & (IDIM - 1);
    int sb = idx >> 8;          // IDIM == 256
    int b  = sb & (BATCH - 1);
    int s  = sb >> 3;           // BATCH == 8
    xt[((size_t)b * SEQ + s) * IDIM + i] = nodes[idx];
}

// ---------------------------------------------------------------------------
// Generic fp32 GEMM: C[M,N] = A[M,K] @ W[N,K]^T + bias[N], optional ReLU.
// 64x64 tile, TK=16, 256 threads, 4x4 outputs/thread. M,N %64==0, K %16==0.
__global__ __launch_bounds__(256) void gemm_bias(const float* __restrict__ A,
                                                 const float* __restrict__ W,
                                                 const float* __restrict__ bias,
                                                 float* __restrict__ C,
                                                 int M, int N, int K, int relu) {
    __shared__ float As[64][17];
    __shared__ float Ws[64][17];
    const int tx = threadIdx.x & 15;
    const int ty = threadIdx.x >> 4;
    const int m0 = blockIdx.y * 64;
    const int n0 = blockIdx.x * 64;
    float acc[4][4] = {};
    for (int k0 = 0; k0 < K; k0 += 16) {
        for (int l = threadIdx.x; l < 64 * 16; l += 256) {
            int mm = l >> 4, kk = l & 15;
            As[mm][kk] = A[(size_t)(m0 + mm) * K + k0 + kk];
            Ws[mm][kk] = W[(size_t)(n0 + mm) * K + k0 + kk];
        }
        __syncthreads();
#pragma unroll
        for (int kk = 0; kk < 16; kk++) {
            float a[4], w[4];
#pragma unroll
            for (int i = 0; i < 4; i++) a[i] = As[ty + i * 16][kk];
#pragma unroll
            for (int j = 0; j < 4; j++) w[j] = Ws[tx + j * 16][kk];
#pragma unroll
            for (int i = 0; i < 4; i++)
#pragma unroll
                for (int j = 0; j < 4; j++) acc[i][j] += a[i] * w[j];
        }
        __syncthreads();
    }
#pragma unroll
    for (int i = 0; i < 4; i++) {
        int m = m0 + ty + i * 16;
#pragma unroll
        for (int j = 0; j < 4; j++) {
            int n = n0 + tx + j * 16;
            float v = acc[i][j] + bias[n];
            if (relu) v = fmaxf(v, 0.f);
            C[(size_t)m * N + n] = v;
        }
    }
}

// ---------------------------------------------------------------------------
// y = LN(x + r) * g + b   over rows of length HDIM=512. r may be null.
// One block (256 threads) per row; in-place safe (y may alias x).
__global__ __launch_bounds__(256) void ln_kernel(const float* __restrict__ x,
                                                 const float* __restrict__ r,
                                                 const float* __restrict__ g,
                                                 const float* __restrict__ b,
                                                 float* __restrict__ y) {
    const size_t base = (size_t)blockIdx.x * HDIM;
    const int t = threadIdx.x;
    float v0 = x[base + t]       + (r ? r[base + t]       : 0.f);
    float v1 = x[base + t + 256] + (r ? r[base + t + 256] : 0.f);
    float s = v0 + v1, ss = v0 * v0 + v1 * v1;
#pragma unroll
    for (int off = 32; off; off >>= 1) {
        s  += __shfl_down(s, off);
        ss += __shfl_down(ss, off);
    }
    __shared__ float sbuf[4], ssbuf[4];
    int wave = t >> 6;
    if ((t & 63) == 0) { sbuf[wave] = s; ssbuf[wave] = ss; }
    __syncthreads();
    if (t == 0) {
        float S1 = 0, S2 = 0;
        for (int w = 0; w < 4; w++) { S1 += sbuf[w]; S2 += ssbuf[w]; }
        sbuf[0] = S1; ssbuf[0] = S2;
    }
    __syncthreads();
    const float mean = sbuf[0] * (1.f / HDIM);
    const float var  = ssbuf[0] * (1.f / HDIM) - mean * mean;
    const float inv  = rsqrtf(var + EPS);
    y[base + t]       = (v0 - mean) * inv * g[t] + b[t];
    y[base + t + 256] = (v1 - mean) * inv * g[t + 256] + b[t + 256];
}

// ---------------------------------------------------------------------------
// Flash attention, fp32. grid = (SEQ/32, NH, BATCH), 256 threads.
// qkv: (B,S,3H) rows; out: (B,S,H). Mask bias computed from dist on the fly.
__global__ __launch_bounds__(256) void attn_kernel(const float* __restrict__ qkv,
                                                   const int* __restrict__ dist,
                                                   float* __restrict__ out) {
    const int q0 = blockIdx.x * 32;
    const int h  = blockIdx.y;
    const int b  = blockIdx.z;
    const int tid = threadIdx.x;

    __shared__ float Qs[32][HD + 1];
    __shared__ float Ks[32][HD + 1];
    __shared__ float Vs[32][HD];
    __shared__ float Ss[32][33];

    const float scale = 0.125f;   // 1/sqrt(64)
    for (int l = tid; l < 32 * HD; l += 256) {
        int rr = l >> 6, d = l & 63;
        Qs[rr][d] = qkv[((size_t)b * SEQ + (q0 + rr)) * (3 * HDIM) + h * HD + d] * scale;
    }
    const int r = tid >> 3;        // q-row within tile (0..31)
    const int j = tid & 7;         // 8 threads cooperate per row
    const int d0 = j * 8;          // this thread's 8 output dims
    const int qrow = q0 + r;
    float m_i = -INFINITY, l_i = 0.f;
    float acc[8] = {};
    __syncthreads();

    for (int kt = 0; kt < SEQ; kt += 32) {
        for (int l = tid; l < 32 * HD; l += 256) {
            int rr = l >> 6, d = l & 63;
            size_t rowb = ((size_t)b * SEQ + (kt + rr)) * (3 * HDIM);
            Ks[rr][d] = qkv[rowb + HDIM + h * HD + d];
            Vs[rr][d] = qkv[rowb + 2 * HDIM + h * HD + d];
        }
        __syncthreads();

        float sc[4];
#pragma unroll
        for (int cc = 0; cc < 4; cc++) {
            int c = j * 4 + cc;
            float s = 0.f;
#pragma unroll
            for (int d = 0; d < HD; d++) s += Qs[r][d] * Ks[c][d];
            int k = kt + c;
            int dd = dist[((size_t)b * SEQ + qrow) * SEQ + k];
            bool allowed;
            if (h < 4)      allowed = (dd == 1);
            else if (h < 6) allowed = (dd >= 1);
            else            allowed = (dist[(size_t)b * SEQ * SEQ + k] >= 1);
            allowed = allowed || (qrow == k);
            sc[cc] = allowed ? s : NEG;
        }
        float tmax = fmaxf(fmaxf(sc[0], sc[1]), fmaxf(sc[2], sc[3]));
#pragma unroll
        for (int off = 4; off; off >>= 1) tmax = fmaxf(tmax, __shfl_xor(tmax, off, 8));
        float new_m = fmaxf(m_i, tmax);
        float alpha = __expf(m_i - new_m);
        float psum = 0.f;
#pragma unroll
        for (int cc = 0; cc < 4; cc++) {
            float p = __expf(sc[cc] - new_m);
            psum += p;
            Ss[r][j * 4 + cc] = p;   // row's 8 threads are one wave-subgroup: no barrier needed
        }
#pragma unroll
        for (int off = 4; off; off >>= 1) psum += __shfl_xor(psum, off, 8);
        l_i = l_i * alpha + psum;
        m_i = new_m;
#pragma unroll
        for (int d = 0; d < 8; d++) acc[d] *= alpha;

        for (int c = 0; c < 32; c++) {
            float p = Ss[r][c];
#pragma unroll
            for (int d = 0; d < 8; d++) acc[d] += p * Vs[c][d0 + d];
        }
        __syncthreads();
    }
    const float inv_l = 1.f / l_i;
#pragma unroll
    for (int d = 0; d < 8; d++)
        out[((size_t)b * SEQ + qrow) * HDIM + h * HD + d0 + d] = acc[d] * inv_l;
}

// ---------------------------------------------------------------------------
// hidden = x[:,0,:]; batchnorm over B=8; out (B,H)
__global__ __launch_bounds__(256) void final_bn(const float* __restrict__ X,
                                                const float* __restrict__ g,
                                                const float* __restrict__ bb,
                                                float* __restrict__ out) {
    int h = blockIdx.x * 256 + threadIdx.x;
    if (h >= HDIM) return;
    float vals[BATCH];
    float m = 0.f;
#pragma unroll
    for (int b = 0; b < BATCH; b++) {
        vals[b] = X[(size_t)b * SEQ * HDIM + h];
        m += vals[b];
    }
    m *= (1.f / BATCH);
    float v = 0.f;
#pragma unroll
    for (int b = 0; b < BATCH; b++) { float d = vals[b] - m; v += d * d; }
    v *= (1.f / BATCH);
    float inv = rsqrtf(v + EPS);
#pragma unroll
    for (int b = 0; b < BATCH; b++)
        out[b * HDIM + h] = (vals[b] - m) * inv * g[h] + bb[h];
}

// ---------------------------------------------------------------------------
extern "C" void kernel_launch(void* const* d_in, const int* in_sizes, int n_in,
                              void* d_out, int out_size, void* d_ws, size_t ws_size,
                              hipStream_t stream) {
    const float* nodes      = (const float*)d_in[0];
    const int*   dist       = (const int*)  d_in[1];
    const float* dense_w    = (const float*)d_in[2];
    const float* dense_b    = (const float*)d_in[3];
    const float* dense_ln_g = (const float*)d_in[4];
    const float* dense_ln_b = (const float*)d_in[5];
    const float* qkv_w      = (const float*)d_in[6];
    const float* qkv_b      = (const float*)d_in[7];
    const float* out_w      = (const float*)d_in[8];
    const float* out_b      = (const float*)d_in[9];
    const float* ln1_g      = (const float*)d_in[10];
    const float* ln1_b      = (const float*)d_in[11];
    const float* ffn_w1     = (const float*)d_in[12];
    const float* ffn_b1     = (const float*)d_in[13];
    const float* ffn_w2     = (const float*)d_in[14];
    const float* ffn_b2     = (const float*)d_in[15];
    const float* ln2_g      = (const float*)d_in[16];
    const float* ln2_b      = (const float*)d_in[17];
    const float* bn_g       = (const float*)d_in[18];
    const float* bn_b       = (const float*)d_in[19];
    float* out = (float*)d_out;

    const int M = BATCH * SEQ;                 // 8192
    char* ws = (char*)d_ws;
    float* X   = (float*)(ws);                                   // 16 MB  (B,S,H)
    float* QKV = (float*)(ws + (size_t)16 * 1024 * 1024);        // 48 MB  (B,S,3H) / reused as F1
    float* AT  = (float*)(ws + (size_t)64 * 1024 * 1024);        // 16 MB  attn out / reused as F2
    float* O2  = (float*)(ws + (size_t)80 * 1024 * 1024);        // 16 MB  out-proj / XT staging

    // 1) transpose nodes -> O2 (used as XT, 8 MB)
    transpose_nodes<<<(SEQ * BATCH * IDIM) / 256, 256, 0, stream>>>(nodes, O2);
    // 2) dense: X = XT @ dense_w^T + dense_b
    gemm_bias<<<dim3(HDIM / 64, M / 64), 256, 0, stream>>>(O2, dense_w, dense_b, X,
                                                           M, HDIM, IDIM, 0);
    // 3) X = LN(X)
    ln_kernel<<<M, 256, 0, stream>>>(X, nullptr, dense_ln_g, dense_ln_b, X);

    for (int l = 0; l < LAYERS; l++) {
        const float* wqkv = qkv_w + (size_t)l * 3 * HDIM * HDIM;
        const float* bqkv = qkv_b + (size_t)l * 3 * HDIM;
        const float* wo   = out_w + (size_t)l * HDIM * HDIM;
        const float* bo   = out_b + (size_t)l * HDIM;
        const float* w1   = ffn_w1 + (size_t)l * FF * HDIM;
        const float* b1   = ffn_b1 + (size_t)l * FF;
        const float* w2   = ffn_w2 + (size_t)l * HDIM * FF;
        const float* b2   = ffn_b2 + (size_t)l * HDIM;

        // qkv = X @ wqkv^T + bqkv
        gemm_bias<<<dim3(3 * HDIM / 64, M / 64), 256, 0, stream>>>(X, wqkv, bqkv, QKV,
                                                                   M, 3 * HDIM, HDIM, 0);
        // attention -> AT
        attn_kernel<<<dim3(SEQ / 32, NH, BATCH), 256, 0, stream>>>(QKV, dist, AT);
        // o = AT @ wo^T + bo -> O2
        gemm_bias<<<dim3(HDIM / 64, M / 64), 256, 0, stream>>>(AT, wo, bo, O2,
                                                               M, HDIM, HDIM, 0);
        // X = LN(X + O2)
        ln_kernel<<<M, 256, 0, stream>>>(X, O2, ln1_g + l * HDIM, ln1_b + l * HDIM, X);
        // F1 = relu(X @ w1^T + b1)  (F1 lives in QKV region)
        gemm_bias<<<dim3(FF / 64, M / 64), 256, 0, stream>>>(X, w1, b1, QKV,
                                                             M, FF, HDIM, 1);
        // F2 = F1 @ w2^T + b2  (F2 lives in AT region)
        gemm_bias<<<dim3(HDIM / 64, M / 64), 256, 0, stream>>>(QKV, w2, b2, AT,
                                                               M, HDIM, FF, 0);
        // X = LN(X + F2)
        ln_kernel<<<M, 256, 0, stream>>>(X, AT, ln2_g + l * HDIM, ln2_b + l * HDIM, X);
    }
    // final batchnorm over batch on x[:,0,:]
    final_bn<<<(HDIM + 255) / 256, 256, 0, stream>>>(X, bn_g, bn_b, out);
}

// Round 2
// 798.074 us; speedup vs baseline: 14.9186x; 14.9186x over previous
//
#include <hip/hip_runtime.h>
#include <hip/hip_bf16.h>
#include <math.h>

#define LAYERS 4
#define IDIM 256
#define HDIM 512
#define NH 8
#define HD 64
#define FF 1024
#define SEQ 1024
#define BATCH 8
#define EPS 1e-5f

typedef __attribute__((ext_vector_type(8))) short short8;
typedef __attribute__((ext_vector_type(4))) short short4v;
typedef __attribute__((ext_vector_type(4))) float f32x4;
typedef unsigned long long u64;

// fp32 -> bf16 (RNE) on raw bits
__device__ __forceinline__ short f2bf(float f) {
    unsigned u = __float_as_uint(f);
    u = (u + 0x7FFFu + ((u >> 16) & 1u)) >> 16;
    return (short)u;
}
__device__ __forceinline__ float bf2f(short s) {
    return __uint_as_float(((unsigned)(unsigned short)s) << 16);
}
// async 16B global->LDS (wave-uniform LDS base + lane*16)
__device__ __forceinline__ void gll16(const void* g, void* l) {
    __builtin_amdgcn_global_load_lds(
        (const __attribute__((address_space(1))) unsigned int*)g,
        (__attribute__((address_space(3))) unsigned int*)l, 16, 0, 0);
}

// ---------------------------------------------------------------------------
// fp32 -> bf16 convert (n multiple of 256)
__global__ __launch_bounds__(256) void cvt_bf16(const float* __restrict__ in,
                                                short* __restrict__ out) {
    size_t i = (size_t)blockIdx.x * 256 + threadIdx.x;
    out[i] = f2bf(in[i]);
}

// nodes (S,B,I) fp32 -> xt (B*S, I) bf16
__global__ __launch_bounds__(256) void transpose_nodes(const float* __restrict__ nodes,
                                                       short* __restrict__ xt) {
    size_t idx = (size_t)blockIdx.x * 256 + threadIdx.x;
    int i  = idx & (IDIM - 1);
    int sb = idx >> 8;
    int b  = sb & (BATCH - 1);
    int s  = sb >> 3;
    xt[((size_t)b * SEQ + s) * IDIM + i] = f2bf(nodes[idx]);
}

// ---------------------------------------------------------------------------
// per-(b,q) 64-bit key masks: short (dd==1), long (dd>=1), global (dist[b][0][k]>=1)
__global__ __launch_bounds__(256) void build_masks(const int* __restrict__ dist,
                                                   u64* __restrict__ mS,
                                                   u64* __restrict__ mL,
                                                   u64* __restrict__ mG) {
    int t = blockIdx.x * 256 + threadIdx.x;      // B*S*16 = 131072
    int w = t & 15, q = (t >> 4) & 1023, b = t >> 14;
    const int* dp = dist + ((size_t)b * SEQ + q) * SEQ + w * 64;
    u64 bs = 0, bl = 0;
    for (int i = 0; i < 64; i++) {
        int d = dp[i];
        bs |= (u64)(d == 1) << i;
        bl |= (u64)(d >= 1) << i;
    }
    mS[((size_t)b * SEQ + q) * 16 + w] = bs;
    mL[((size_t)b * SEQ + q) * 16 + w] = bl;
    if (q == 0) mG[b * 16 + w] = bl;
}

// ---------------------------------------------------------------------------
// bf16 MFMA GEMM: C[M,N](bf16) = A[M,K](bf16) @ W[N,K]^T(bf16) + bias(f32), opt ReLU
// BM x 128 tile, BK=64, 256 threads. XOR-swizzled LDS, global_load_lds staging.
template<int BM>
__global__ __launch_bounds__(256, 2)
void gemm_bf16(const short* __restrict__ A, const short* __restrict__ W,
               const float* __restrict__ bias, short* __restrict__ C,
               int M, int N, int K, int relu) {
    __shared__ __align__(16) short As[BM * 64];
    __shared__ __align__(16) short Ws[128 * 64];
    const int tid = threadIdx.x;
    const int w = tid >> 6, lane = tid & 63;
    const int l15 = lane & 15, quad = lane >> 4;
    const int m0 = blockIdx.y * BM, n0 = blockIdx.x * 128;

    constexpr int NI = (BM == 128) ? 4 : 2;
    const int wm = (BM == 128) ? (w >> 1) * 64 : 0;
    const int wn = (BM == 128) ? (w & 1) * 64 : w * 32;

    f32x4 acc[4][NI];
#pragma unroll
    for (int mi = 0; mi < 4; mi++)
#pragma unroll
        for (int ni = 0; ni < NI; ni++) acc[mi][ni] = (f32x4){0.f, 0.f, 0.f, 0.f};

    const int r_in = lane >> 3;   // 8 rows per 1KB chunk
    const int c8   = lane & 7;    // 16B block within row

    for (int k0 = 0; k0 < K; k0 += 64) {
        // stage A tile (BM x 64) and W tile (128 x 64), 16B swizzled by row&7
#pragma unroll
        for (int rep = 0; rep < BM * 8 / 256; rep++) {
            int chunk = rep * 4 + w;
            int row = chunk * 8 + r_in;
            const short* src = A + (size_t)(m0 + row) * K + k0 + ((c8 ^ (row & 7)) << 3);
            gll16(src, (char*)As + chunk * 1024);
        }
#pragma unroll
        for (int rep = 0; rep < 4; rep++) {
            int chunk = rep * 4 + w;
            int row = chunk * 8 + r_in;
            const short* src = W + (size_t)(n0 + row) * K + k0 + ((c8 ^ (row & 7)) << 3);
            gll16(src, (char*)Ws + chunk * 1024);
        }
        __syncthreads();
#pragma unroll
        for (int ks = 0; ks < 2; ks++) {
            short8 af[4], wf[NI];
            const int dblk = ks * 4 + quad;
#pragma unroll
            for (int mi = 0; mi < 4; mi++) {
                int row = wm + mi * 16 + l15;
                af[mi] = *(const short8*)((const char*)As + row * 128 + ((dblk ^ (row & 7)) << 4));
            }
#pragma unroll
            for (int ni = 0; ni < NI; ni++) {
                int row = wn + ni * 16 + l15;
                wf[ni] = *(const short8*)((const char*)Ws + row * 128 + ((dblk ^ (row & 7)) << 4));
            }
#pragma unroll
            for (int mi = 0; mi < 4; mi++)
#pragma unroll
                for (int ni = 0; ni < NI; ni++)
                    acc[mi][ni] = __builtin_amdgcn_mfma_f32_16x16x32_bf16(
                        af[mi], wf[ni], acc[mi][ni], 0, 0, 0);
        }
        __syncthreads();
    }
    // epilogue: bias (+relu), bf16 store. C/D: col=lane&15, row=quad*4+reg
#pragma unroll
    for (int ni = 0; ni < NI; ni++) {
        int n = n0 + wn + ni * 16 + l15;
        float bz = bias[n];
#pragma unroll
        for (int mi = 0; mi < 4; mi++) {
#pragma unroll
            for (int r = 0; r < 4; r++) {
                int m = m0 + wm + mi * 16 + quad * 4 + r;
                float v = acc[mi][ni][r] + bz;
                if (relu) v = fmaxf(v, 0.f);
                C[(size_t)m * N + n] = f2bf(v);
            }
        }
    }
}

// ---------------------------------------------------------------------------
// V-transpose: QKV raw (B,S,3H) V-section -> Vt (B,NH,HD,S) bf16
__global__ __launch_bounds__(256) void v_transpose(const short* __restrict__ qkv,
                                                   short* __restrict__ vt) {
    const int s0 = blockIdx.x * 64, h = blockIdx.y, b = blockIdx.z;
    __shared__ __align__(16) short T[64 * 72];
    const int tid = threadIdx.x;
#pragma unroll
    for (int rep = 0; rep < 2; rep++) {
        int item = tid + rep * 256;
        int sl = item >> 3, c = item & 7;
        short8 v = *(const short8*)(qkv + ((size_t)(b * SEQ + s0 + sl) * 1536) + 1024 + h * 64 + c * 8);
        *(short8*)(T + sl * 72 + c * 8) = v;
    }
    __syncthreads();
    int d = tid & 63, g = tid >> 6;      // row d, col group g*16
    short8 o0, o1;
#pragma unroll
    for (int i = 0; i < 8; i++) o0[i] = T[(g * 16 + i) * 72 + d];
#pragma unroll
    for (int i = 0; i < 8; i++) o1[i] = T[(g * 16 + 8 + i) * 72 + d];
    short* dst = vt + ((size_t)((b * NH + h) * HD + d) * SEQ) + s0 + g * 16;
    *(short8*)dst = o0;
    *(short8*)(dst + 8) = o1;
}

// ---------------------------------------------------------------------------
// MFMA flash attention. grid (S/64, NH, B), 256 thr (4 waves x 16 q-rows).
// S^T = K.Q^T  (stats per-lane since col=q=lane&15);  O^T = V^T.P^T.
__global__ __launch_bounds__(256, 3)
void attn_mfma(const short* __restrict__ qkv, const short* __restrict__ vt,
               const u64* __restrict__ maskS, const u64* __restrict__ maskL,
               const u64* __restrict__ maskG, short* __restrict__ out) {
    const int tid = threadIdx.x;
    const int w = tid >> 6, lane = tid & 63, l15 = lane & 15, quad = lane >> 4;
    const int h = blockIdx.y, b = blockIdx.z;
    const int q = blockIdx.x * 64 + w * 16 + l15;     // this lane's q-row

    __shared__ __align__(16) short Ks[64 * 64];
    __shared__ __align__(16) short Vs[64 * 64];

    short8 qf[2];
    {
        const short* qrow = qkv + ((size_t)(b * SEQ + q) * 1536) + h * 64;
#pragma unroll
        for (int ks = 0; ks < 2; ks++)
            qf[ks] = *(const short8*)(qrow + ks * 32 + quad * 8);
    }
    const u64* mrow = (h < 4) ? (maskS + ((size_t)b * SEQ + q) * 16)
                   : (h < 6) ? (maskL + ((size_t)b * SEQ + q) * 16)
                   :           (maskG + (size_t)b * 16);

    f32x4 of[4];
#pragma unroll
    for (int mt = 0; mt < 4; mt++) of[mt] = (f32x4){0.f, 0.f, 0.f, 0.f};
    float m_i = -INFINITY, l_i = 0.f;

    const int r_in = lane >> 3, c8 = lane & 7;
    for (int kt = 0; kt < SEQ; kt += 64) {
        // stage K (rows=key, 64 d) and V^T (rows=d, 64 keys), swizzled
#pragma unroll
        for (int rep = 0; rep < 2; rep++) {
            int chunk = rep * 4 + w;
            int row = chunk * 8 + r_in;
            const short* ksrc = qkv + ((size_t)(b * SEQ + kt + row) * 1536) + 512 + h * 64 + ((c8 ^ (row & 7)) << 3);
            gll16(ksrc, (char*)Ks + chunk * 1024);
            const short* vsrc = vt + ((size_t)((b * NH + h) * HD + row) * SEQ) + kt + ((c8 ^ (row & 7)) << 3);
            gll16(vsrc, (char*)Vs + chunk * 1024);
        }
        __syncthreads();

        // S^T tiles: 4 key-groups x (2 ksteps over d)
        f32x4 sa[4];
#pragma unroll
        for (int g = 0; g < 4; g++) sa[g] = (f32x4){0.f, 0.f, 0.f, 0.f};
#pragma unroll
        for (int ks = 0; ks < 2; ks++) {
            const int dblk = ks * 4 + quad;
#pragma unroll
            for (int g = 0; g < 4; g++) {
                int row = g * 16 + l15;
                short8 kf = *(const short8*)((const char*)Ks + row * 128 + ((dblk ^ (row & 7)) << 4));
                sa[g] = __builtin_amdgcn_mfma_f32_16x16x32_bf16(kf, qf[ks], sa[g], 0, 0, 0);
            }
        }
        // mask + scale + online softmax (stats per q = lane&15; reduce over quads)
        u64 mw = mrow[kt >> 6];
        if ((q >> 6) == (kt >> 6)) mw |= 1ull << (q & 63);
        float p[4][4];
        float tmax = -INFINITY;
#pragma unroll
        for (int g = 0; g < 4; g++)
#pragma unroll
            for (int r = 0; r < 4; r++) {
                int key = g * 16 + quad * 4 + r;
                float s = sa[g][r] * 0.125f + (((mw >> key) & 1ull) ? 0.f : -1e9f);
                p[g][r] = s;
                tmax = fmaxf(tmax, s);
            }
        tmax = fmaxf(tmax, __shfl_xor(tmax, 16));
        tmax = fmaxf(tmax, __shfl_xor(tmax, 32));
        float mnew = fmaxf(m_i, tmax);
        float alpha = __expf(m_i - mnew);
        float ps = 0.f;
#pragma unroll
        for (int g = 0; g < 4; g++)
#pragma unroll
            for (int r = 0; r < 4; r++) {
                p[g][r] = __expf(p[g][r] - mnew);
                ps += p[g][r];
            }
        ps += __shfl_xor(ps, 16);
        ps += __shfl_xor(ps, 32);
        l_i = l_i * alpha + ps;
        m_i = mnew;
#pragma unroll
        for (int mt = 0; mt < 4; mt++) of[mt] *= alpha;

        // P^T C-layout -> B-frags via cross-quad shuffles
        short8 pf[2];
#pragma unroll
        for (int ks = 0; ks < 2; ks++) {
#pragma unroll
            for (int j = 0; j < 8; j++) {
                int src = (((quad & 1) * 2 + (j >> 2)) << 4) | l15;
                float lo = __shfl(p[2 * ks][j & 3], src);
                float hi = __shfl(p[2 * ks + 1][j & 3], src);
                pf[ks][j] = f2bf((quad < 2) ? lo : hi);
            }
        }
        // O^T += V^T . P^T
#pragma unroll
        for (int ks = 0; ks < 2; ks++) {
            const int dblk = ks * 4 + quad;
#pragma unroll
            for (int mt = 0; mt < 4; mt++) {
                int row = mt * 16 + l15;
                short8 vf = *(const short8*)((const char*)Vs + row * 128 + ((dblk ^ (row & 7)) << 4));
                of[mt] = __builtin_amdgcn_mfma_f32_16x16x32_bf16(vf, pf[ks], of[mt], 0, 0, 0);
            }
        }
        __syncthreads();
    }
    float inv = 1.f / l_i;
#pragma unroll
    for (int mt = 0; mt < 4; mt++) {
        short4v pk;
#pragma unroll
        for (int r = 0; r < 4; r++) pk[r] = f2bf(of[mt][r] * inv);
        *(short4v*)(out + ((size_t)(b * SEQ + q) * HDIM) + h * 64 + mt * 16 + quad * 4) = pk;
    }
}

// ---------------------------------------------------------------------------
// y = LN(x + r) * g + b over rows of 512, bf16 in/out, fp32 math. r may be null.
__global__ __launch_bounds__(256) void ln_bf16(const short* __restrict__ x,
                                               const short* __restrict__ r,
                                               const float* __restrict__ g,
                                               const float* __restrict__ b,
                                               short* __restrict__ y) {
    const size_t base = (size_t)blockIdx.x * HDIM;
    const int t = threadIdx.x;
    float v0 = bf2f(x[base + t])       + (r ? bf2f(r[base + t])       : 0.f);
    float v1 = bf2f(x[base + t + 256]) + (r ? bf2f(r[base + t + 256]) : 0.f);
    float s = v0 + v1, ss = v0 * v0 + v1 * v1;
#pragma unroll
    for (int off = 32; off; off >>= 1) {
        s  += __shfl_down(s, off);
        ss += __shfl_down(ss, off);
    }
    __shared__ float sbuf[4], ssbuf[4];
    int wave = t >> 6;
    if ((t & 63) == 0) { sbuf[wave] = s; ssbuf[wave] = ss; }
    __syncthreads();
    if (t == 0) {
        float S1 = 0, S2 = 0;
        for (int wv = 0; wv < 4; wv++) { S1 += sbuf[wv]; S2 += ssbuf[wv]; }
        sbuf[0] = S1; ssbuf[0] = S2;
    }
    __syncthreads();
    const float mean = sbuf[0] * (1.f / HDIM);
    const float var  = ssbuf[0] * (1.f / HDIM) - mean * mean;
    const float inv  = rsqrtf(var + EPS);
    y[base + t]       = f2bf((v0 - mean) * inv * g[t] + b[t]);
    y[base + t + 256] = f2bf((v1 - mean) * inv * g[t + 256] + b[t + 256]);
}

// ---------------------------------------------------------------------------
__global__ __launch_bounds__(256) void final_bn(const short* __restrict__ X,
                                                const float* __restrict__ g,
                                                const float* __restrict__ bb,
                                                float* __restrict__ out) {
    int h = blockIdx.x * 256 + threadIdx.x;
    if (h >= HDIM) return;
    float vals[BATCH];
    float m = 0.f;
#pragma unroll
    for (int b = 0; b < BATCH; b++) {
        vals[b] = bf2f(X[(size_t)b * SEQ * HDIM + h]);
        m += vals[b];
    }
    m *= (1.f / BATCH);
    float v = 0.f;
#pragma unroll
    for (int b = 0; b < BATCH; b++) { float d = vals[b] - m; v += d * d; }
    v *= (1.f / BATCH);
    float inv = rsqrtf(v + EPS);
#pragma unroll
    for (int b = 0; b < BATCH; b++)
        out[b * HDIM + h] = (vals[b] - m) * inv * g[h] + bb[h];
}

// ---------------------------------------------------------------------------
extern "C" void kernel_launch(void* const* d_in, const int* in_sizes, int n_in,
                              void* d_out, int out_size, void* d_ws, size_t ws_size,
                              hipStream_t stream) {
    const float* nodes      = (const float*)d_in[0];
    const int*   dist       = (const int*)  d_in[1];
    const float* dense_w    = (const float*)d_in[2];
    const float* dense_b    = (const float*)d_in[3];
    const float* dense_ln_g = (const float*)d_in[4];
    const float* dense_ln_b = (const float*)d_in[5];
    const float* qkv_w      = (const float*)d_in[6];
    const float* qkv_b      = (const float*)d_in[7];
    const float* out_w      = (const float*)d_in[8];
    const float* out_b      = (const float*)d_in[9];
    const float* ln1_g      = (const float*)d_in[10];
    const float* ln1_b      = (const float*)d_in[11];
    const float* ffn_w1     = (const float*)d_in[12];
    const float* ffn_b1     = (const float*)d_in[13];
    const float* ffn_w2     = (const float*)d_in[14];
    const float* ffn_b2     = (const float*)d_in[15];
    const float* ln2_g      = (const float*)d_in[16];
    const float* ln2_b      = (const float*)d_in[17];
    const float* bn_g       = (const float*)d_in[18];
    const float* bn_b       = (const float*)d_in[19];
    float* out = (float*)d_out;

    const int M = BATCH * SEQ;                         // 8192
    const size_t MB = 1024 * 1024;
    char* ws = (char*)d_ws;
    short* Wd   = (short*)(ws + 0 * MB);               // 256 KB
    short* Wqkv = (short*)(ws + 1 * MB);               // 6 MB
    short* Wo   = (short*)(ws + 9 * MB);               // 2 MB
    short* W1   = (short*)(ws + 13 * MB);              // 4 MB
    short* W2   = (short*)(ws + 18 * MB);              // 4 MB
    u64*   mS   = (u64*)(ws + 23 * MB);                // 1 MB
    u64*   mL   = (u64*)(ws + 24 * MB);                // 1 MB
    u64*   mG   = (u64*)(ws + 25 * MB);                // 1 KB
    short* X    = (short*)(ws + 26 * MB);              // 8 MB
    short* QKV  = (short*)(ws + 34 * MB);              // 24 MB (also XT, F1)
    short* Vt   = (short*)(ws + 58 * MB);              // 8 MB
    short* AT   = (short*)(ws + 66 * MB);              // 8 MB (also F2)
    short* O2   = (short*)(ws + 74 * MB);              // 8 MB
    short* XT   = QKV;
    short* F1   = QKV;
    short* F2   = AT;

    // weight conversions (sizes all multiples of 256)
    cvt_bf16<<<(HDIM * IDIM) / 256, 256, 0, stream>>>(dense_w, Wd);
    cvt_bf16<<<(LAYERS * 3 * HDIM * HDIM) / 256, 256, 0, stream>>>(qkv_w, Wqkv);
    cvt_bf16<<<(LAYERS * HDIM * HDIM) / 256, 256, 0, stream>>>(out_w, Wo);
    cvt_bf16<<<(LAYERS * FF * HDIM) / 256, 256, 0, stream>>>(ffn_w1, W1);
    cvt_bf16<<<(LAYERS * HDIM * FF) / 256, 256, 0, stream>>>(ffn_w2, W2);

    transpose_nodes<<<(SEQ * BATCH * IDIM) / 256, 256, 0, stream>>>(nodes, XT);
    build_masks<<<(BATCH * SEQ * 16) / 256, 256, 0, stream>>>(dist, mS, mL, mG);

    // dense: O2 = XT @ Wd^T + b ; X = LN(O2)
    gemm_bf16<64><<<dim3(HDIM / 128, M / 64), 256, 0, stream>>>(XT, Wd, dense_b, O2,
                                                                M, HDIM, IDIM, 0);
    ln_bf16<<<M, 256, 0, stream>>>(O2, nullptr, dense_ln_g, dense_ln_b, X);

    for (int l = 0; l < LAYERS; l++) {
        const short* wqkv = Wqkv + (size_t)l * 3 * HDIM * HDIM;
        const float* bqkv = qkv_b + (size_t)l * 3 * HDIM;
        const short* wo   = Wo + (size_t)l * HDIM * HDIM;
        const float* bo   = out_b + (size_t)l * HDIM;
        const short* w1   = W1 + (size_t)l * FF * HDIM;
        const float* b1   = ffn_b1 + (size_t)l * FF;
        const short* w2   = W2 + (size_t)l * HDIM * FF;
        const float* b2   = ffn_b2 + (size_t)l * HDIM;

        gemm_bf16<128><<<dim3(3 * HDIM / 128, M / 128), 256, 0, stream>>>(
            X, wqkv, bqkv, QKV, M, 3 * HDIM, HDIM, 0);
        v_transpose<<<dim3(SEQ / 64, NH, BATCH), 256, 0, stream>>>(QKV, Vt);
        attn_mfma<<<dim3(SEQ / 64, NH, BATCH), 256, 0, stream>>>(QKV, Vt, mS, mL, mG, AT);
        gemm_bf16<64><<<dim3(HDIM / 128, M / 64), 256, 0, stream>>>(
            AT, wo, bo, O2, M, HDIM, HDIM, 0);
        ln_bf16<<<M, 256, 0, stream>>>(X, O2, ln1_g + l * HDIM, ln1_b + l * HDIM, X);
        gemm_bf16<128><<<dim3(FF / 128, M / 128), 256, 0, stream>>>(
            X, w1, b1, F1, M, FF, HDIM, 1);
        gemm_bf16<64><<<dim3(HDIM / 128, M / 64), 256, 0, stream>>>(
            F1, w2, b2, F2, M, HDIM, FF, 0);
        ln_bf16<<<M, 256, 0, stream>>>(X, F2, ln2_g + l * HDIM, ln2_b + l * HDIM, X);
    }
    final_bn<<<(HDIM + 255) / 256, 256, 0, stream>>>(X, bn_g, bn_b, out);
}

// Round 3
// 656.571 us; speedup vs baseline: 18.1338x; 1.2155x over previous
//
#include <hip/hip_runtime.h>
#include <hip/hip_bf16.h>
#include <math.h>

#define LAYERS 4
#define IDIM 256
#define HDIM 512
#define NH 8
#define HD 64
#define FF 1024
#define SEQ 1024
#define BATCH 8
#define EPS 1e-5f

typedef __attribute__((ext_vector_type(8))) short short8;
typedef __attribute__((ext_vector_type(4))) short short4v;
typedef __attribute__((ext_vector_type(4))) float f32x4;
typedef unsigned long long u64;

// fp32 -> bf16 (RNE) on raw bits
__device__ __forceinline__ short f2bf(float f) {
    unsigned u = __float_as_uint(f);
    u = (u + 0x7FFFu + ((u >> 16) & 1u)) >> 16;
    return (short)u;
}
__device__ __forceinline__ float bf2f(short s) {
    return __uint_as_float(((unsigned)(unsigned short)s) << 16);
}
__device__ __forceinline__ void gll16(const void* g, void* l) {
    __builtin_amdgcn_global_load_lds(
        (const __attribute__((address_space(1))) unsigned int*)g,
        (__attribute__((address_space(3))) unsigned int*)l, 16, 0, 0);
}

// ---------------------------------------------------------------------------
// fp32 -> bf16 convert, 4 elems/thread (n multiple of 1024)
__global__ __launch_bounds__(256) void cvt_bf16(const float* __restrict__ in,
                                                short* __restrict__ out) {
    size_t i = ((size_t)blockIdx.x * 256 + threadIdx.x) * 4;
    f32x4 f = *(const f32x4*)(in + i);
    short4v o = {f2bf(f[0]), f2bf(f[1]), f2bf(f[2]), f2bf(f[3])};
    *(short4v*)(out + i) = o;
}

// nodes (S,B,I) fp32 -> xt (B*S, I) bf16, 4 elems/thread
__global__ __launch_bounds__(256) void transpose_nodes(const float* __restrict__ nodes,
                                                       short* __restrict__ xt) {
    size_t idx = ((size_t)blockIdx.x * 256 + threadIdx.x) * 4;
    int i  = idx & (IDIM - 1);
    int sb = idx >> 8;
    int b  = sb & (BATCH - 1);
    int s  = sb >> 3;
    f32x4 f = *(const f32x4*)(nodes + idx);
    short4v o = {f2bf(f[0]), f2bf(f[1]), f2bf(f[2]), f2bf(f[3])};
    *(short4v*)(xt + ((size_t)b * SEQ + s) * IDIM + i) = o;
}

// ---------------------------------------------------------------------------
__global__ __launch_bounds__(256) void build_masks(const int* __restrict__ dist,
                                                   u64* __restrict__ mS,
                                                   u64* __restrict__ mL,
                                                   u64* __restrict__ mG) {
    int t = blockIdx.x * 256 + threadIdx.x;      // B*S*16 = 131072
    int w = t & 15, q = (t >> 4) & 1023, b = t >> 14;
    const int* dp = dist + ((size_t)b * SEQ + q) * SEQ + w * 64;
    u64 bs = 0, bl = 0;
    for (int i = 0; i < 64; i++) {
        int d = dp[i];
        bs |= (u64)(d == 1) << i;
        bl |= (u64)(d >= 1) << i;
    }
    mS[((size_t)b * SEQ + q) * 16 + w] = bs;
    mL[((size_t)b * SEQ + q) * 16 + w] = bl;
    if (q == 0) mG[b * 16 + w] = bl;
}

// ---------------------------------------------------------------------------
// bf16 MFMA GEMM: C[M,N](bf16) = A[M,K](bf16) @ W[N,K]^T(bf16) + bias(f32), opt ReLU
template<int BM>
__global__ __launch_bounds__(256, 2)
void gemm_bf16(const short* __restrict__ A, const short* __restrict__ W,
               const float* __restrict__ bias, short* __restrict__ C,
               int M, int N, int K, int relu) {
    __shared__ __align__(16) short As[BM * 64];
    __shared__ __align__(16) short Ws[128 * 64];
    const int tid = threadIdx.x;
    const int w = tid >> 6, lane = tid & 63;
    const int l15 = lane & 15, quad = lane >> 4;
    const int m0 = blockIdx.y * BM, n0 = blockIdx.x * 128;

    constexpr int NI = (BM == 128) ? 4 : 2;
    const int wm = (BM == 128) ? (w >> 1) * 64 : 0;
    const int wn = (BM == 128) ? (w & 1) * 64 : w * 32;

    f32x4 acc[4][NI];
#pragma unroll
    for (int mi = 0; mi < 4; mi++)
#pragma unroll
        for (int ni = 0; ni < NI; ni++) acc[mi][ni] = (f32x4){0.f, 0.f, 0.f, 0.f};

    const int r_in = lane >> 3;
    const int c8   = lane & 7;

    for (int k0 = 0; k0 < K; k0 += 64) {
#pragma unroll
        for (int rep = 0; rep < BM * 8 / 256; rep++) {
            int chunk = rep * 4 + w;
            int row = chunk * 8 + r_in;
            const short* src = A + (size_t)(m0 + row) * K + k0 + ((c8 ^ (row & 7)) << 3);
            gll16(src, (char*)As + chunk * 1024);
        }
#pragma unroll
        for (int rep = 0; rep < 4; rep++) {
            int chunk = rep * 4 + w;
            int row = chunk * 8 + r_in;
            const short* src = W + (size_t)(n0 + row) * K + k0 + ((c8 ^ (row & 7)) << 3);
            gll16(src, (char*)Ws + chunk * 1024);
        }
        __syncthreads();
#pragma unroll
        for (int ks = 0; ks < 2; ks++) {
            short8 af[4], wf[NI];
            const int dblk = ks * 4 + quad;
#pragma unroll
            for (int mi = 0; mi < 4; mi++) {
                int row = wm + mi * 16 + l15;
                af[mi] = *(const short8*)((const char*)As + row * 128 + ((dblk ^ (row & 7)) << 4));
            }
#pragma unroll
            for (int ni = 0; ni < NI; ni++) {
                int row = wn + ni * 16 + l15;
                wf[ni] = *(const short8*)((const char*)Ws + row * 128 + ((dblk ^ (row & 7)) << 4));
            }
#pragma unroll
            for (int mi = 0; mi < 4; mi++)
#pragma unroll
                for (int ni = 0; ni < NI; ni++)
                    acc[mi][ni] = __builtin_amdgcn_mfma_f32_16x16x32_bf16(
                        af[mi], wf[ni], acc[mi][ni], 0, 0, 0);
        }
        __syncthreads();
    }
#pragma unroll
    for (int ni = 0; ni < NI; ni++) {
        int n = n0 + wn + ni * 16 + l15;
        float bz = bias[n];
#pragma unroll
        for (int mi = 0; mi < 4; mi++) {
#pragma unroll
            for (int r = 0; r < 4; r++) {
                int m = m0 + wm + mi * 16 + quad * 4 + r;
                float v = acc[mi][ni][r] + bz;
                if (relu) v = fmaxf(v, 0.f);
                C[(size_t)m * N + n] = f2bf(v);
            }
        }
    }
}

// ---------------------------------------------------------------------------
// V-transpose: QKV raw (B,S,3H) V-section -> Vt (B,NH,HD,S) bf16
__global__ __launch_bounds__(256) void v_transpose(const short* __restrict__ qkv,
                                                   short* __restrict__ vt) {
    const int s0 = blockIdx.x * 64, h = blockIdx.y, b = blockIdx.z;
    __shared__ __align__(16) short T[64 * 72];
    const int tid = threadIdx.x;
#pragma unroll
    for (int rep = 0; rep < 2; rep++) {
        int item = tid + rep * 256;
        int sl = item >> 3, c = item & 7;
        short8 v = *(const short8*)(qkv + ((size_t)(b * SEQ + s0 + sl) * 1536) + 1024 + h * 64 + c * 8);
        *(short8*)(T + sl * 72 + c * 8) = v;
    }
    __syncthreads();
    int d = tid & 63, g = tid >> 6;
    short8 o0, o1;
#pragma unroll
    for (int i = 0; i < 8; i++) o0[i] = T[(g * 16 + i) * 72 + d];
#pragma unroll
    for (int i = 0; i < 8; i++) o1[i] = T[(g * 16 + 8 + i) * 72 + d];
    short* dst = vt + ((size_t)((b * NH + h) * HD + d) * SEQ) + s0 + g * 16;
    *(short8*)dst = o0;
    *(short8*)(dst + 8) = o1;
}

// ---------------------------------------------------------------------------
// MFMA flash attention, max-free softmax, zero-shuffle P^T handoff.
// 1D grid of 1024 blocks, XCD-swizzled so 16 q-tiles of one (b,h) share an XCD.
// S^T = K.Q^T (16x16x32): stats land per-lane (col=q=lane&15).
// O^T = V^T.P^T via 16x16x16: B-frag k=quad*4+j == C-layout row=quad*4+r.
#define EXP2SC 0.18033688011112042f   /* 0.125 * log2(e) */
__global__ __launch_bounds__(256, 3)
void attn_mfma(const short* __restrict__ qkv, const short* __restrict__ vt,
               const u64* __restrict__ maskS, const u64* __restrict__ maskL,
               const u64* __restrict__ maskG, short* __restrict__ out) {
    const int tid = threadIdx.x;
    const int w = tid >> 6, lane = tid & 63, l15 = lane & 15, quad = lane >> 4;
    // XCD-swizzle decode: groups of 16 q-tiles land on one XCD (id%8 heuristic)
    const int p = blockIdx.x;
    const int g_ = (p & 7) + 8 * (p >> 7);          // (b,h) group 0..63
    const int qt = (p >> 3) & 15;                   // q-tile 0..15
    const int b = g_ >> 3, h = g_ & 7;
    const int q = qt * 64 + w * 16 + l15;

    __shared__ __align__(16) short Ks[64 * 64];
    __shared__ __align__(16) short Vs[64 * 64];

    short8 qf[2];
    {
        const short* qrow = qkv + ((size_t)(b * SEQ + q) * 1536) + h * 64;
#pragma unroll
        for (int ks = 0; ks < 2; ks++)
            qf[ks] = *(const short8*)(qrow + ks * 32 + quad * 8);
    }
    const u64* mrow = (h < 4) ? (maskS + ((size_t)b * SEQ + q) * 16)
                   : (h < 6) ? (maskL + ((size_t)b * SEQ + q) * 16)
                   :           (maskG + (size_t)b * 16);

    f32x4 of[4];
#pragma unroll
    for (int mt = 0; mt < 4; mt++) of[mt] = (f32x4){0.f, 0.f, 0.f, 0.f};
    float lsum = 0.f;

    const int r_in = lane >> 3, c8 = lane & 7;
    for (int kt = 0; kt < SEQ; kt += 64) {
#pragma unroll
        for (int rep = 0; rep < 2; rep++) {
            int chunk = rep * 4 + w;
            int row = chunk * 8 + r_in;
            const short* ksrc = qkv + ((size_t)(b * SEQ + kt + row) * 1536) + 512 + h * 64 + ((c8 ^ (row & 7)) << 3);
            gll16(ksrc, (char*)Ks + chunk * 1024);
            const short* vsrc = vt + ((size_t)((b * NH + h) * HD + row) * SEQ) + kt + ((c8 ^ (row & 7)) << 3);
            gll16(vsrc, (char*)Vs + chunk * 1024);
        }
        __syncthreads();

        // S^T tiles (keys x q)
        f32x4 sa[4];
#pragma unroll
        for (int g = 0; g < 4; g++) sa[g] = (f32x4){0.f, 0.f, 0.f, 0.f};
#pragma unroll
        for (int ks = 0; ks < 2; ks++) {
            const int dblk = ks * 4 + quad;
#pragma unroll
            for (int g = 0; g < 4; g++) {
                int row = g * 16 + l15;
                short8 kf = *(const short8*)((const char*)Ks + row * 128 + ((dblk ^ (row & 7)) << 4));
                sa[g] = __builtin_amdgcn_mfma_f32_16x16x32_bf16(kf, qf[ks], sa[g], 0, 0, 0);
            }
        }
        // max-free masked softmax numerator; pack directly into PV B-frags
        u64 mw = mrow[kt >> 6];
        if ((q >> 6) == (kt >> 6)) mw |= 1ull << (q & 63);
#if __has_builtin(__builtin_amdgcn_mfma_f32_16x16x16bf16_1k)
        short4v pfrag[4];
#pragma unroll
        for (int g = 0; g < 4; g++)
#pragma unroll
            for (int r = 0; r < 4; r++) {
                int key = g * 16 + quad * 4 + r;
                float bias = ((mw >> key) & 1ull) ? 0.f : -1e9f;
                float pv = exp2f(fmaf(sa[g][r], EXP2SC, bias));
                lsum += pv;
                pfrag[g][r] = f2bf(pv);
            }
        // O^T += V^T . P^T   (16x16x16, K=16 per key-group)
#pragma unroll
        for (int g = 0; g < 4; g++) {
            const int blk = (g << 1) + (quad >> 1);
#pragma unroll
            for (int mt = 0; mt < 4; mt++) {
                int row = mt * 16 + l15;
                short4v vf = *(const short4v*)((const char*)Vs + row * 128 +
                                               ((blk ^ (row & 7)) << 4) + ((quad & 1) << 3));
                of[mt] = __builtin_amdgcn_mfma_f32_16x16x16bf16_1k(vf, pfrag[g], of[mt], 0, 0, 0);
            }
        }
#else
        float pp[4][4];
#pragma unroll
        for (int g = 0; g < 4; g++)
#pragma unroll
            for (int r = 0; r < 4; r++) {
                int key = g * 16 + quad * 4 + r;
                float bias = ((mw >> key) & 1ull) ? 0.f : -1e9f;
                float pv = exp2f(fmaf(sa[g][r], EXP2SC, bias));
                lsum += pv;
                pp[g][r] = pv;
            }
        short8 pf[2];
#pragma unroll
        for (int ks = 0; ks < 2; ks++) {
#pragma unroll
            for (int j = 0; j < 8; j++) {
                int src = (((quad & 1) * 2 + (j >> 2)) << 4) | l15;
                float lo = __shfl(pp[2 * ks][j & 3], src);
                float hi = __shfl(pp[2 * ks + 1][j & 3], src);
                pf[ks][j] = f2bf((quad < 2) ? lo : hi);
            }
        }
#pragma unroll
        for (int ks = 0; ks < 2; ks++) {
            const int dblk = ks * 4 + quad;
#pragma unroll
            for (int mt = 0; mt < 4; mt++) {
                int row = mt * 16 + l15;
                short8 vf = *(const short8*)((const char*)Vs + row * 128 + ((dblk ^ (row & 7)) << 4));
                of[mt] = __builtin_amdgcn_mfma_f32_16x16x32_bf16(vf, pf[ks], of[mt], 0, 0, 0);
            }
        }
#endif
        __syncthreads();
    }
    lsum += __shfl_xor(lsum, 16);
    lsum += __shfl_xor(lsum, 32);
    float inv = 1.f / lsum;
#pragma unroll
    for (int mt = 0; mt < 4; mt++) {
        short4v pk;
#pragma unroll
        for (int r = 0; r < 4; r++) pk[r] = f2bf(of[mt][r] * inv);
        *(short4v*)(out + ((size_t)(b * SEQ + q) * HDIM) + h * 64 + mt * 16 + quad * 4) = pk;
    }
}

// ---------------------------------------------------------------------------
// y = LN(x + r)*g + b, rows of 512. One wave per row (lane holds 8 elems).
__global__ __launch_bounds__(256) void ln_bf16(const short* __restrict__ x,
                                               const short* __restrict__ r,
                                               const float* __restrict__ g,
                                               const float* __restrict__ b,
                                               short* __restrict__ y) {
    const int wv = threadIdx.x >> 6, lane = threadIdx.x & 63;
    const size_t row = (size_t)blockIdx.x * 4 + wv;
    const size_t base = row * HDIM + lane * 8;
    short8 xv = *(const short8*)(x + base);
    float v[8];
#pragma unroll
    for (int i = 0; i < 8; i++) v[i] = bf2f(xv[i]);
    if (r) {
        short8 rv = *(const short8*)(r + base);
#pragma unroll
        for (int i = 0; i < 8; i++) v[i] += bf2f(rv[i]);
    }
    float s = 0.f, ss = 0.f;
#pragma unroll
    for (int i = 0; i < 8; i++) { s += v[i]; ss += v[i] * v[i]; }
#pragma unroll
    for (int off = 1; off < 64; off <<= 1) {
        s  += __shfl_xor(s, off);
        ss += __shfl_xor(ss, off);
    }
    const float mean = s * (1.f / HDIM);
    const float var  = ss * (1.f / HDIM) - mean * mean;
    const float inv  = rsqrtf(var + EPS);
    f32x4 g0 = *(const f32x4*)(g + lane * 8), g1 = *(const f32x4*)(g + lane * 8 + 4);
    f32x4 b0 = *(const f32x4*)(b + lane * 8), b1 = *(const f32x4*)(b + lane * 8 + 4);
    short8 o;
#pragma unroll
    for (int i = 0; i < 4; i++) o[i]     = f2bf((v[i]     - mean) * inv * g0[i] + b0[i]);
#pragma unroll
    for (int i = 0; i < 4; i++) o[i + 4] = f2bf((v[i + 4] - mean) * inv * g1[i] + b1[i]);
    *(short8*)(y + base) = o;
}

// ---------------------------------------------------------------------------
__global__ __launch_bounds__(256) void final_bn(const short* __restrict__ X,
                                                const float* __restrict__ g,
                                                const float* __restrict__ bb,
                                                float* __restrict__ out) {
    int h = blockIdx.x * 256 + threadIdx.x;
    if (h >= HDIM) return;
    float vals[BATCH];
    float m = 0.f;
#pragma unroll
    for (int b = 0; b < BATCH; b++) {
        vals[b] = bf2f(X[(size_t)b * SEQ * HDIM + h]);
        m += vals[b];
    }
    m *= (1.f / BATCH);
    float v = 0.f;
#pragma unroll
    for (int b = 0; b < BATCH; b++) { float d = vals[b] - m; v += d * d; }
    v *= (1.f / BATCH);
    float inv = rsqrtf(v + EPS);
#pragma unroll
    for (int b = 0; b < BATCH; b++)
        out[b * HDIM + h] = (vals[b] - m) * inv * g[h] + bb[h];
}

// ---------------------------------------------------------------------------
extern "C" void kernel_launch(void* const* d_in, const int* in_sizes, int n_in,
                              void* d_out, int out_size, void* d_ws, size_t ws_size,
                              hipStream_t stream) {
    const float* nodes      = (const float*)d_in[0];
    const int*   dist       = (const int*)  d_in[1];
    const float* dense_w    = (const float*)d_in[2];
    const float* dense_b    = (const float*)d_in[3];
    const float* dense_ln_g = (const float*)d_in[4];
    const float* dense_ln_b = (const float*)d_in[5];
    const float* qkv_w      = (const float*)d_in[6];
    const float* qkv_b      = (const float*)d_in[7];
    const float* out_w      = (const float*)d_in[8];
    const float* out_b      = (const float*)d_in[9];
    const float* ln1_g      = (const float*)d_in[10];
    const float* ln1_b      = (const float*)d_in[11];
    const float* ffn_w1     = (const float*)d_in[12];
    const float* ffn_b1     = (const float*)d_in[13];
    const float* ffn_w2     = (const float*)d_in[14];
    const float* ffn_b2     = (const float*)d_in[15];
    const float* ln2_g      = (const float*)d_in[16];
    const float* ln2_b      = (const float*)d_in[17];
    const float* bn_g       = (const float*)d_in[18];
    const float* bn_b       = (const float*)d_in[19];
    float* out = (float*)d_out;

    const int M = BATCH * SEQ;                         // 8192
    const size_t MB = 1024 * 1024;
    char* ws = (char*)d_ws;
    short* Wd   = (short*)(ws + 0 * MB);
    short* Wqkv = (short*)(ws + 1 * MB);
    short* Wo   = (short*)(ws + 9 * MB);
    short* W1   = (short*)(ws + 13 * MB);
    short* W2   = (short*)(ws + 18 * MB);
    u64*   mS   = (u64*)(ws + 23 * MB);
    u64*   mL   = (u64*)(ws + 24 * MB);
    u64*   mG   = (u64*)(ws + 25 * MB);
    short* X    = (short*)(ws + 26 * MB);
    short* QKV  = (short*)(ws + 34 * MB);
    short* Vt   = (short*)(ws + 58 * MB);
    short* AT   = (short*)(ws + 66 * MB);
    short* O2   = (short*)(ws + 74 * MB);
    short* XT   = QKV;
    short* F1   = QKV;
    short* F2   = AT;

    cvt_bf16<<<(HDIM * IDIM) / 1024, 256, 0, stream>>>(dense_w, Wd);
    cvt_bf16<<<(LAYERS * 3 * HDIM * HDIM) / 1024, 256, 0, stream>>>(qkv_w, Wqkv);
    cvt_bf16<<<(LAYERS * HDIM * HDIM) / 1024, 256, 0, stream>>>(out_w, Wo);
    cvt_bf16<<<(LAYERS * FF * HDIM) / 1024, 256, 0, stream>>>(ffn_w1, W1);
    cvt_bf16<<<(LAYERS * HDIM * FF) / 1024, 256, 0, stream>>>(ffn_w2, W2);

    transpose_nodes<<<(SEQ * BATCH * IDIM) / 1024, 256, 0, stream>>>(nodes, XT);
    build_masks<<<(BATCH * SEQ * 16) / 256, 256, 0, stream>>>(dist, mS, mL, mG);

    gemm_bf16<64><<<dim3(HDIM / 128, M / 64), 256, 0, stream>>>(XT, Wd, dense_b, O2,
                                                                M, HDIM, IDIM, 0);
    ln_bf16<<<M / 4, 256, 0, stream>>>(O2, nullptr, dense_ln_g, dense_ln_b, X);

    for (int l = 0; l < LAYERS; l++) {
        const short* wqkv = Wqkv + (size_t)l * 3 * HDIM * HDIM;
        const float* bqkv = qkv_b + (size_t)l * 3 * HDIM;
        const short* wo   = Wo + (size_t)l * HDIM * HDIM;
        const float* bo   = out_b + (size_t)l * HDIM;
        const short* w1   = W1 + (size_t)l * FF * HDIM;
        const float* b1   = ffn_b1 + (size_t)l * FF;
        const short* w2   = W2 + (size_t)l * HDIM * FF;
        const float* b2   = ffn_b2 + (size_t)l * HDIM;

        gemm_bf16<128><<<dim3(3 * HDIM / 128, M / 128), 256, 0, stream>>>(
            X, wqkv, bqkv, QKV, M, 3 * HDIM, HDIM, 0);
        v_transpose<<<dim3(SEQ / 64, NH, BATCH), 256, 0, stream>>>(QKV, Vt);
        attn_mfma<<<1024, 256, 0, stream>>>(QKV, Vt, mS, mL, mG, AT);
        gemm_bf16<64><<<dim3(HDIM / 128, M / 64), 256, 0, stream>>>(
            AT, wo, bo, O2, M, HDIM, HDIM, 0);
        ln_bf16<<<M / 4, 256, 0, stream>>>(X, O2, ln1_g + l * HDIM, ln1_b + l * HDIM, X);
        gemm_bf16<128><<<dim3(FF / 128, M / 128), 256, 0, stream>>>(
            X, w1, b1, F1, M, FF, HDIM, 1);
        gemm_bf16<64><<<dim3(HDIM / 128, M / 64), 256, 0, stream>>>(
            F1, w2, b2, F2, M, HDIM, FF, 0);
        ln_bf16<<<M / 4, 256, 0, stream>>>(X, F2, ln2_g + l * HDIM, ln2_b + l * HDIM, X);
    }
    final_bn<<<(HDIM + 255) / 256, 256, 0, stream>>>(X, bn_g, bn_b, out);
}

// Round 5
// 644.991 us; speedup vs baseline: 18.4593x; 1.0180x over previous
//
#include <hip/hip_runtime.h>
#include <hip/hip_bf16.h>
#include <math.h>

#define LAYERS 4
#define IDIM 256
#define HDIM 512
#define NH 8
#define HD 64
#define FF 1024
#define SEQ 1024
#define BATCH 8
#define EPS 1e-5f

typedef __attribute__((ext_vector_type(8))) short short8;
typedef __attribute__((ext_vector_type(4))) short short4v;
typedef __attribute__((ext_vector_type(4))) float f32x4;
typedef __attribute__((ext_vector_type(4))) int int4v;
typedef __attribute__((ext_vector_type(2))) unsigned int uint2v;
typedef unsigned long long u64;

// fp32 -> bf16 (RNE) on raw bits
__device__ __forceinline__ short f2bf(float f) {
    unsigned u = __float_as_uint(f);
    u = (u + 0x7FFFu + ((u >> 16) & 1u)) >> 16;
    return (short)u;
}
__device__ __forceinline__ float bf2f(short s) {
    return __uint_as_float(((unsigned)(unsigned short)s) << 16);
}
__device__ __forceinline__ void gll16(const void* g, void* l) {
    __builtin_amdgcn_global_load_lds(
        (const __attribute__((address_space(1))) unsigned int*)g,
        (__attribute__((address_space(3))) unsigned int*)l, 16, 0, 0);
}

// ---------------------------------------------------------------------------
// merged fp32->bf16 conversion of all 5 weight tensors, 4 elems/thread.
// Prefix sums (elements): dense_w 131072 | qkv_w 3145728 | out_w 1048576 |
// ffn_w1 2097152 | ffn_w2 2097152  -> total 8519680.
#define CVT_P0 131072u
#define CVT_P1 3276800u
#define CVT_P2 4325376u
#define CVT_P3 6422528u
#define CVT_TOT 8519680u
__global__ __launch_bounds__(256) void cvt_all(const float* __restrict__ s0, short* __restrict__ d0,
                                               const float* __restrict__ s1, short* __restrict__ d1,
                                               const float* __restrict__ s2, short* __restrict__ d2,
                                               const float* __restrict__ s3, short* __restrict__ d3,
                                               const float* __restrict__ s4, short* __restrict__ d4) {
    size_t i = ((size_t)blockIdx.x * 256 + threadIdx.x) * 4;
    const float* s; short* d; size_t off;
    if (i < CVT_P0)      { s = s0; d = d0; off = i; }
    else if (i < CVT_P1) { s = s1; d = d1; off = i - CVT_P0; }
    else if (i < CVT_P2) { s = s2; d = d2; off = i - CVT_P1; }
    else if (i < CVT_P3) { s = s3; d = d3; off = i - CVT_P2; }
    else                 { s = s4; d = d4; off = i - CVT_P3; }
    f32x4 f = *(const f32x4*)(s + off);
    short4v o = {f2bf(f[0]), f2bf(f[1]), f2bf(f[2]), f2bf(f[3])};
    *(short4v*)(d + off) = o;
}

// nodes (S,B,I) fp32 -> xt (B*S, I) bf16, 4 elems/thread
__global__ __launch_bounds__(256) void transpose_nodes(const float* __restrict__ nodes,
                                                       short* __restrict__ xt) {
    size_t idx = ((size_t)blockIdx.x * 256 + threadIdx.x) * 4;
    int i  = idx & (IDIM - 1);
    int sb = idx >> 8;
    int b  = sb & (BATCH - 1);
    int s  = sb >> 3;
    f32x4 f = *(const f32x4*)(nodes + idx);
    short4v o = {f2bf(f[0]), f2bf(f[1]), f2bf(f[2]), f2bf(f[3])};
    *(short4v*)(xt + ((size_t)b * SEQ + s) * IDIM + i) = o;
}

// ---------------------------------------------------------------------------
__global__ __launch_bounds__(256) void build_masks(const int* __restrict__ dist,
                                                   u64* __restrict__ mS,
                                                   u64* __restrict__ mL,
                                                   u64* __restrict__ mG) {
    int t = blockIdx.x * 256 + threadIdx.x;      // B*S*16 = 131072
    int w = t & 15, q = (t >> 4) & 1023, b = t >> 14;
    const int4v* dp = (const int4v*)(dist + ((size_t)b * SEQ + q) * SEQ + w * 64);
    u64 bs = 0, bl = 0;
#pragma unroll
    for (int i = 0; i < 16; i++) {
        int4v d = dp[i];
#pragma unroll
        for (int j = 0; j < 4; j++) {
            bs |= (u64)(d[j] == 1) << (i * 4 + j);
            bl |= (u64)(d[j] >= 1) << (i * 4 + j);
        }
    }
    mS[((size_t)b * SEQ + q) * 16 + w] = bs;
    mL[((size_t)b * SEQ + q) * 16 + w] = bl;
    if (q == 0) mG[b * 16 + w] = bl;
}

// ---------------------------------------------------------------------------
// bf16 MFMA GEMM: C[M,N](bf16) = A[M,K](bf16) @ W[N,K]^T(bf16) + bias(f32), opt ReLU.
// If vt != null, column blocks with n0 >= 1024 are the V-projection: written to
// Vt (B,NH,HD,S) in paired-chunk layout (16B unit u of each 64-key tile holds
// keys {16g+4q..+3 , 16(g+2)+4q..+3} where u = 4g+q) instead of C.
template<int BM>
__global__ __launch_bounds__(256, 2)
void gemm_bf16(const short* __restrict__ A, const short* __restrict__ W,
               const float* __restrict__ bias, short* __restrict__ C,
               short* __restrict__ vt, int M, int N, int K, int relu) {
    __shared__ __align__(16) short As[BM * 64];
    __shared__ __align__(16) short Ws[128 * 64];
    const int tid = threadIdx.x;
    const int w = tid >> 6, lane = tid & 63;
    const int l15 = lane & 15, quad = lane >> 4;
    const int m0 = blockIdx.y * BM, n0 = blockIdx.x * 128;

    constexpr int NI = (BM == 128) ? 4 : 2;
    const int wm = (BM == 128) ? (w >> 1) * 64 : 0;
    const int wn = (BM == 128) ? (w & 1) * 64 : w * 32;

    f32x4 acc[4][NI];
#pragma unroll
    for (int mi = 0; mi < 4; mi++)
#pragma unroll
        for (int ni = 0; ni < NI; ni++) acc[mi][ni] = (f32x4){0.f, 0.f, 0.f, 0.f};

    const int r_in = lane >> 3;
    const int c8   = lane & 7;

    for (int k0 = 0; k0 < K; k0 += 64) {
#pragma unroll
        for (int rep = 0; rep < BM * 8 / 256; rep++) {
            int chunk = rep * 4 + w;
            int row = chunk * 8 + r_in;
            const short* src = A + (size_t)(m0 + row) * K + k0 + ((c8 ^ (row & 7)) << 3);
            gll16(src, (char*)As + chunk * 1024);
        }
#pragma unroll
        for (int rep = 0; rep < 4; rep++) {
            int chunk = rep * 4 + w;
            int row = chunk * 8 + r_in;
            const short* src = W + (size_t)(n0 + row) * K + k0 + ((c8 ^ (row & 7)) << 3);
            gll16(src, (char*)Ws + chunk * 1024);
        }
        __syncthreads();
#pragma unroll
        for (int ks = 0; ks < 2; ks++) {
            short8 af[4], wf[NI];
            const int dblk = ks * 4 + quad;
#pragma unroll
            for (int mi = 0; mi < 4; mi++) {
                int row = wm + mi * 16 + l15;
                af[mi] = *(const short8*)((const char*)As + row * 128 + ((dblk ^ (row & 7)) << 4));
            }
#pragma unroll
            for (int ni = 0; ni < NI; ni++) {
                int row = wn + ni * 16 + l15;
                wf[ni] = *(const short8*)((const char*)Ws + row * 128 + ((dblk ^ (row & 7)) << 4));
            }
#pragma unroll
            for (int mi = 0; mi < 4; mi++)
#pragma unroll
                for (int ni = 0; ni < NI; ni++)
                    acc[mi][ni] = __builtin_amdgcn_mfma_f32_16x16x32_bf16(
                        af[mi], wf[ni], acc[mi][ni], 0, 0, 0);
        }
        __syncthreads();
    }
    if (vt && n0 >= 1024) {
        // V-projection epilogue: write transposed into paired-chunk Vt layout
#pragma unroll
        for (int ni = 0; ni < NI; ni++) {
            int n = n0 + wn + ni * 16 + l15;
            int d = n - 1024, h = d >> 6, dd = d & 63;
            float bz = bias[n];
#pragma unroll
            for (int mi = 0; mi < 4; mi++) {
                int mbase = m0 + wm + mi * 16 + quad * 4;   // 4 consecutive s
                int b = mbase >> 10, s = mbase & 1023;
                int tile = s >> 6, j = (s & 63) >> 2;       // chunk index 0..15
                size_t off = ((size_t)(b * NH + h) * HD + dd) * SEQ
                           + tile * 64 + (j & 7) * 8 + (j >> 3) * 4;
                short4v pk;
#pragma unroll
                for (int r = 0; r < 4; r++) pk[r] = f2bf(acc[mi][ni][r] + bz);
                *(short4v*)(vt + off) = pk;
            }
        }
    } else {
#pragma unroll
        for (int ni = 0; ni < NI; ni++) {
            int n = n0 + wn + ni * 16 + l15;
            float bz = bias[n];
#pragma unroll
            for (int mi = 0; mi < 4; mi++) {
#pragma unroll
                for (int r = 0; r < 4; r++) {
                    int m = m0 + wm + mi * 16 + quad * 4 + r;
                    float v = acc[mi][ni][r] + bz;
                    if (relu) v = fmaxf(v, 0.f);
                    C[(size_t)m * N + n] = f2bf(v);
                }
            }
        }
    }
}

// ---------------------------------------------------------------------------
// MFMA flash attention, max-free softmax, zero-shuffle P^T handoff, paired-chunk
// V^T layout so PV V-frags are conflict-free ds_read_b128 (each feeds 2 MFMAs).
#define EXP2SC 0.18033688011112042f   /* 0.125 * log2(e) */
__global__ __launch_bounds__(256, 4)
void attn_mfma(const short* __restrict__ qkv, const short* __restrict__ vt,
               const u64* __restrict__ maskS, const u64* __restrict__ maskL,
               const u64* __restrict__ maskG, short* __restrict__ out) {
    const int tid = threadIdx.x;
    const int w = tid >> 6, lane = tid & 63, l15 = lane & 15, quad = lane >> 4;
    const int p = blockIdx.x;
    const int g_ = (p & 7) + 8 * (p >> 7);          // (b,h) group, XCD-swizzled
    const int qt = (p >> 3) & 15;
    const int b = g_ >> 3, h = g_ & 7;
    const int q = qt * 64 + w * 16 + l15;

    __shared__ __align__(16) short Ks[64 * 64];
    __shared__ __align__(16) short Vs[64 * 64];

    short8 qf[2];
    {
        const short* qrow = qkv + ((size_t)(b * SEQ + q) * 1536) + h * 64;
#pragma unroll
        for (int ks = 0; ks < 2; ks++)
            qf[ks] = *(const short8*)(qrow + ks * 32 + quad * 8);
    }
    const u64* mrow = (h < 4) ? (maskS + ((size_t)b * SEQ + q) * 16)
                   : (h < 6) ? (maskL + ((size_t)b * SEQ + q) * 16)
                   :           (maskG + (size_t)b * 16);

    f32x4 of[4];
#pragma unroll
    for (int mt = 0; mt < 4; mt++) of[mt] = (f32x4){0.f, 0.f, 0.f, 0.f};
    float lsum = 0.f;

    const int r_in = lane >> 3, c8 = lane & 7;
    for (int kt = 0; kt < SEQ; kt += 64) {
#pragma unroll
        for (int rep = 0; rep < 2; rep++) {
            int chunk = rep * 4 + w;
            int row = chunk * 8 + r_in;
            const short* ksrc = qkv + ((size_t)(b * SEQ + kt + row) * 1536) + 512 + h * 64 + ((c8 ^ (row & 7)) << 3);
            gll16(ksrc, (char*)Ks + chunk * 1024);
            const short* vsrc = vt + ((size_t)((b * NH + h) * HD + row) * SEQ) + kt + ((c8 ^ (row & 7)) << 3);
            gll16(vsrc, (char*)Vs + chunk * 1024);
        }
        __syncthreads();

        // S^T tiles (keys x q)
        f32x4 sa[4];
#pragma unroll
        for (int g = 0; g < 4; g++) sa[g] = (f32x4){0.f, 0.f, 0.f, 0.f};
#pragma unroll
        for (int ks = 0; ks < 2; ks++) {
            const int dblk = ks * 4 + quad;
#pragma unroll
            for (int g = 0; g < 4; g++) {
                int row = g * 16 + l15;
                short8 kf = *(const short8*)((const char*)Ks + row * 128 + ((dblk ^ (row & 7)) << 4));
                sa[g] = __builtin_amdgcn_mfma_f32_16x16x32_bf16(kf, qf[ks], sa[g], 0, 0, 0);
            }
        }
        // max-free masked softmax numerator; perm-truncate pack into B-frags
        u64 mw = mrow[kt >> 6];
        if ((q >> 6) == (kt >> 6)) mw |= 1ull << (q & 63);
        short4v pfrag[4];
#pragma unroll
        for (int g = 0; g < 4; g++) {
            float pv[4];
#pragma unroll
            for (int r = 0; r < 4; r++) {
                int key = g * 16 + quad * 4 + r;
                float bias = ((mw >> key) & 1ull) ? 0.f : -1e9f;
                pv[r] = exp2f(fmaf(sa[g][r], EXP2SC, bias));
                lsum += pv[r];
            }
            uint2v pk;
            pk[0] = __builtin_amdgcn_perm(__float_as_uint(pv[1]), __float_as_uint(pv[0]), 0x07060302u);
            pk[1] = __builtin_amdgcn_perm(__float_as_uint(pv[3]), __float_as_uint(pv[2]), 0x07060302u);
            pfrag[g] = __builtin_bit_cast(short4v, pk);
        }
        // O^T += V^T . P^T : one b128 read feeds groups g01 and g01+2
#pragma unroll
        for (int g01 = 0; g01 < 2; g01++) {
            const int u = g01 * 4 + quad;
#pragma unroll
            for (int mt = 0; mt < 4; mt++) {
                int row = mt * 16 + l15;
                short8 vv = *(const short8*)((const char*)Vs + row * 128 + ((u ^ (row & 7)) << 4));
                short4v vlo = {vv[0], vv[1], vv[2], vv[3]};
                short4v vhi = {vv[4], vv[5], vv[6], vv[7]};
                of[mt] = __builtin_amdgcn_mfma_f32_16x16x16bf16_1k(vlo, pfrag[g01], of[mt], 0, 0, 0);
                of[mt] = __builtin_amdgcn_mfma_f32_16x16x16bf16_1k(vhi, pfrag[g01 + 2], of[mt], 0, 0, 0);
            }
        }
        __syncthreads();
    }
    lsum += __shfl_xor(lsum, 16);
    lsum += __shfl_xor(lsum, 32);
    float inv = 1.f / lsum;
#pragma unroll
    for (int mt = 0; mt < 4; mt++) {
        short4v pk;
#pragma unroll
        for (int r = 0; r < 4; r++) pk[r] = f2bf(of[mt][r] * inv);
        *(short4v*)(out + ((size_t)(b * SEQ + q) * HDIM) + h * 64 + mt * 16 + quad * 4) = pk;
    }
}

// ---------------------------------------------------------------------------
// y = LN(x + r)*g + b, rows of 512. One wave per row (lane holds 8 elems).
__global__ __launch_bounds__(256) void ln_bf16(const short* __restrict__ x,
                                               const short* __restrict__ r,
                                               const float* __restrict__ g,
                                               const float* __restrict__ b,
                                               short* __restrict__ y) {
    const int wv = threadIdx.x >> 6, lane = threadIdx.x & 63;
    const size_t row = (size_t)blockIdx.x * 4 + wv;
    const size_t base = row * HDIM + lane * 8;
    short8 xv = *(const short8*)(x + base);
    float v[8];
#pragma unroll
    for (int i = 0; i < 8; i++) v[i] = bf2f(xv[i]);
    if (r) {
        short8 rv = *(const short8*)(r + base);
#pragma unroll
        for (int i = 0; i < 8; i++) v[i] += bf2f(rv[i]);
    }
    float s = 0.f, ss = 0.f;
#pragma unroll
    for (int i = 0; i < 8; i++) { s += v[i]; ss += v[i] * v[i]; }
#pragma unroll
    for (int off = 1; off < 64; off <<= 1) {
        s  += __shfl_xor(s, off);
        ss += __shfl_xor(ss, off);
    }
    const float mean = s * (1.f / HDIM);
    const float var  = ss * (1.f / HDIM) - mean * mean;
    const float inv  = rsqrtf(var + EPS);
    f32x4 g0 = *(const f32x4*)(g + lane * 8), g1 = *(const f32x4*)(g + lane * 8 + 4);
    f32x4 b0 = *(const f32x4*)(b + lane * 8), b1 = *(const f32x4*)(b + lane * 8 + 4);
    short8 o;
#pragma unroll
    for (int i = 0; i < 4; i++) o[i]     = f2bf((v[i]     - mean) * inv * g0[i] + b0[i]);
#pragma unroll
    for (int i = 0; i < 4; i++) o[i + 4] = f2bf((v[i + 4] - mean) * inv * g1[i] + b1[i]);
    *(short8*)(y + base) = o;
}

// ---------------------------------------------------------------------------
__global__ __launch_bounds__(256) void final_bn(const short* __restrict__ X,
                                                const float* __restrict__ g,
                                                const float* __restrict__ bb,
                                                float* __restrict__ out) {
    int h = blockIdx.x * 256 + threadIdx.x;
    if (h >= HDIM) return;
    float vals[BATCH];
    float m = 0.f;
#pragma unroll
    for (int b = 0; b < BATCH; b++) {
        vals[b] = bf2f(X[(size_t)b * SEQ * HDIM + h]);
        m += vals[b];
    }
    m *= (1.f / BATCH);
    float v = 0.f;
#pragma unroll
    for (int b = 0; b < BATCH; b++) { float d = vals[b] - m; v += d * d; }
    v *= (1.f / BATCH);
    float inv = rsqrtf(v + EPS);
#pragma unroll
    for (int b = 0; b < BATCH; b++)
        out[b * HDIM + h] = (vals[b] - m) * inv * g[h] + bb[h];
}

// ---------------------------------------------------------------------------
extern "C" void kernel_launch(void* const* d_in, const int* in_sizes, int n_in,
                              void* d_out, int out_size, void* d_ws, size_t ws_size,
                              hipStream_t stream) {
    const float* nodes      = (const float*)d_in[0];
    const int*   dist       = (const int*)  d_in[1];
    const float* dense_w    = (const float*)d_in[2];
    const float* dense_b    = (const float*)d_in[3];
    const float* dense_ln_g = (const float*)d_in[4];
    const float* dense_ln_b = (const float*)d_in[5];
    const float* qkv_w      = (const float*)d_in[6];
    const float* qkv_b      = (const float*)d_in[7];
    const float* out_w      = (const float*)d_in[8];
    const float* out_b      = (const float*)d_in[9];
    const float* ln1_g      = (const float*)d_in[10];
    const float* ln1_b      = (const float*)d_in[11];
    const float* ffn_w1     = (const float*)d_in[12];
    const float* ffn_b1     = (const float*)d_in[13];
    const float* ffn_w2     = (const float*)d_in[14];
    const float* ffn_b2     = (const float*)d_in[15];
    const float* ln2_g      = (const float*)d_in[16];
    const float* ln2_b      = (const float*)d_in[17];
    const float* bn_g       = (const float*)d_in[18];
    const float* bn_b       = (const float*)d_in[19];
    float* out = (float*)d_out;

    const int M = BATCH * SEQ;                         // 8192
    const size_t MB = 1024 * 1024;
    char* ws = (char*)d_ws;
    short* Wd   = (short*)(ws + 0 * MB);
    short* Wqkv = (short*)(ws + 1 * MB);
    short* Wo   = (short*)(ws + 9 * MB);
    short* W1   = (short*)(ws + 13 * MB);
    short* W2   = (short*)(ws + 18 * MB);
    u64*   mS   = (u64*)(ws + 23 * MB);
    u64*   mL   = (u64*)(ws + 24 * MB);
    u64*   mG   = (u64*)(ws + 25 * MB);
    short* X    = (short*)(ws + 26 * MB);
    short* QKV  = (short*)(ws + 34 * MB);
    short* Vt   = (short*)(ws + 58 * MB);
    short* AT   = (short*)(ws + 66 * MB);
    short* O2   = (short*)(ws + 74 * MB);
    short* XT   = QKV;
    short* F1   = QKV;
    short* F2   = AT;

    cvt_all<<<CVT_TOT / 1024, 256, 0, stream>>>(dense_w, Wd, qkv_w, Wqkv,
                                                out_w, Wo, ffn_w1, W1, ffn_w2, W2);
    transpose_nodes<<<(SEQ * BATCH * IDIM) / 1024, 256, 0, stream>>>(nodes, XT);
    build_masks<<<(BATCH * SEQ * 16) / 256, 256, 0, stream>>>(dist, mS, mL, mG);

    gemm_bf16<64><<<dim3(HDIM / 128, M / 64), 256, 0, stream>>>(
        XT, Wd, dense_b, O2, nullptr, M, HDIM, IDIM, 0);
    ln_bf16<<<M / 4, 256, 0, stream>>>(O2, nullptr, dense_ln_g, dense_ln_b, X);

    for (int l = 0; l < LAYERS; l++) {
        const short* wqkv = Wqkv + (size_t)l * 3 * HDIM * HDIM;
        const float* bqkv = qkv_b + (size_t)l * 3 * HDIM;
        const short* wo   = Wo + (size_t)l * HDIM * HDIM;
        const float* bo   = out_b + (size_t)l * HDIM;
        const short* w1   = W1 + (size_t)l * FF * HDIM;
        const float* b1   = ffn_b1 + (size_t)l * FF;
        const short* w2   = W2 + (size_t)l * HDIM * FF;
        const float* b2   = ffn_b2 + (size_t)l * HDIM;

        gemm_bf16<128><<<dim3(3 * HDIM / 128, M / 128), 256, 0, stream>>>(
            X, wqkv, bqkv, QKV, Vt, M, 3 * HDIM, HDIM, 0);
        attn_mfma<<<1024, 256, 0, stream>>>(QKV, Vt, mS, mL, mG, AT);
        gemm_bf16<64><<<dim3(HDIM / 128, M / 64), 256, 0, stream>>>(
            AT, wo, bo, O2, nullptr, M, HDIM, HDIM, 0);
        ln_bf16<<<M / 4, 256, 0, stream>>>(X, O2, ln1_g + l * HDIM, ln1_b + l * HDIM, X);
        gemm_bf16<128><<<dim3(FF / 128, M / 128), 256, 0, stream>>>(
            X, w1, b1, F1, nullptr, M, FF, HDIM, 1);
        gemm_bf16<64><<<dim3(HDIM / 128, M / 64), 256, 0, stream>>>(
            F1, w2, b2, F2, nullptr, M, HDIM, FF, 0);
        ln_bf16<<<M / 4, 256, 0, stream>>>(X, F2, ln2_g + l * HDIM, ln2_b + l * HDIM, X);
    }
    final_bn<<<(HDIM + 255) / 256, 256, 0, stream>>>(X, bn_g, bn_b, out);
}